// Round 6
// baseline (29.539 us; speedup 1.0000x reference)
//
#include <hip/hip_runtime.h>
#include <math.h>

#define T_SAMPLES 100
#define K1_BLOCKS 1024
#define HB_MAX 1024       // histogram blocks (4/CU)
#define HB_MIN 512        // u32 pack overflow-safe minimum
#define THREADS 256
#define NWAVES (THREADS / 64)
#define NSUB 16           // one sub-histogram per lane&15 group (4 lanes/wave each)
#define HPAD 101          // odd u32 stride -> 16 subs on 16 distinct banks
#define PART32 4096       // u32 index where transposed partials start
#define FINAL_C_D 54016   // double index: per-bin total counts
#define FINAL_O_D 54144   // double index: per-bin total fixed-point frac sums
// footprint: 4*(4096+100*1024) = 426 KB partials + finals @ ~433 KB  (ws >= ~840 KB known)

// pack: count in bits [23:31] (max 511), frac*2^15 in bits [0:22]
#define CNT_ONE (1u << 23)
#define OFS_MASK ((1u << 23) - 1u)

__global__ void __launch_bounds__(THREADS) cvar_pass1(const float* __restrict__ pnl,
                                                      int n, float* __restrict__ ws) {
    if (blockIdx.x == 0 && threadIdx.x == 0) ((unsigned*)ws)[0] = 0u;  // K3's counter

    int tid = blockIdx.x * THREADS + threadIdx.x;
    int stride = gridDim.x * THREADS;
    float lmin = INFINITY, lmax = -INFINITY;
    int n4 = n >> 2;
    const float4* p4 = (const float4*)pnl;
    for (int i = tid; i < n4; i += stride) {
        float4 v = p4[i];
        lmin = fminf(lmin, fminf(fminf(-v.x, -v.y), fminf(-v.z, -v.w)));
        lmax = fmaxf(lmax, fmaxf(fmaxf(-v.x, -v.y), fmaxf(-v.z, -v.w)));
    }
    for (int i = (n4 << 2) + tid; i < n; i += stride) {
        float l = -pnl[i];
        lmin = fminf(lmin, l);
        lmax = fmaxf(lmax, l);
    }
    #pragma unroll
    for (int off = 32; off > 0; off >>= 1) {
        lmin = fminf(lmin, __shfl_down(lmin, off, 64));
        lmax = fmaxf(lmax, __shfl_down(lmax, off, 64));
    }
    __shared__ float smin[NWAVES], smax[NWAVES];
    int lane = threadIdx.x & 63, wid = threadIdx.x >> 6;
    if (lane == 0) { smin[wid] = lmin; smax[wid] = lmax; }
    __syncthreads();
    if (threadIdx.x == 0) {
        float a = smin[0], b = smax[0];
        for (int w = 1; w < NWAVES; ++w) { a = fminf(a, smin[w]); b = fmaxf(b, smax[w]); }
        ws[16 + blockIdx.x] = a;
        ws[16 + K1_BLOCKS + blockIdx.x] = b;
    }
}

__device__ __forceinline__ void reduce_minmax_partials(const float* __restrict__ ws,
                                                       float* s_tmin, float* s_tmax,
                                                       float* smin, float* smax) {
    float lmin = INFINITY, lmax = -INFINITY;
    for (int i = threadIdx.x; i < K1_BLOCKS; i += blockDim.x) {
        lmin = fminf(lmin, ws[16 + i]);
        lmax = fmaxf(lmax, ws[16 + K1_BLOCKS + i]);
    }
    #pragma unroll
    for (int off = 32; off > 0; off >>= 1) {
        lmin = fminf(lmin, __shfl_down(lmin, off, 64));
        lmax = fmaxf(lmax, __shfl_down(lmax, off, 64));
    }
    int lane = threadIdx.x & 63, wid = threadIdx.x >> 6;
    if (lane == 0) { smin[wid] = lmin; smax[wid] = lmax; }
    __syncthreads();
    if (threadIdx.x == 0) {
        float a = smin[0], b = smax[0];
        int nw = blockDim.x >> 6;
        for (int w = 1; w < nw; ++w) { a = fminf(a, smin[w]); b = fmaxf(b, smax[w]); }
        *s_tmin = a;
        *s_tmax = b;
    }
    __syncthreads();
}

__global__ void __launch_bounds__(THREADS) cvar_pass2(const float* __restrict__ pnl,
                                                      int n, float* __restrict__ ws,
                                                      int nb) {
    __shared__ unsigned h[NSUB * HPAD];
    __shared__ float smin[NWAVES], smax[NWAVES];
    __shared__ float s_tmin, s_tmax;

    for (int i = threadIdx.x; i < NSUB * HPAD; i += THREADS) h[i] = 0u;
    reduce_minmax_partials(ws, &s_tmin, &s_tmax, smin, smax);

    const float t_min = s_tmin, t_max = s_tmax;
    const float range = t_max - t_min;
    const float inv_dt = (range > 0.0f) ? (float)(T_SAMPLES - 1) / range : 0.0f;

    // sub-hist per lane&15: within one ds_add instruction only 4 lanes share a sub
    const int subbase = (threadIdx.x & 15) * HPAD;
    int tid = blockIdx.x * THREADS + threadIdx.x;
    int stride = gridDim.x * THREADS;
    int n4 = n >> 2;
    const float4* p4 = (const float4*)pnl;
    for (int i = tid; i < n4; i += stride) {
        float4 v = p4[i];
        float l[4] = {-v.x, -v.y, -v.z, -v.w};
        #pragma unroll
        for (int k = 0; k < 4; ++k) {
            float x = (l[k] - t_min) * inv_dt;
            int b = (int)x;
            b = b < 0 ? 0 : (b > T_SAMPLES - 1 ? T_SAMPLES - 1 : b);
            unsigned of = (unsigned)(fminf(x - (float)b, 0.99999994f) * 32768.0f);
            atomicAdd(&h[subbase + b], CNT_ONE | of);
        }
    }
    for (int i = (n4 << 2) + tid; i < n; i += stride) {
        float x = (-pnl[i] - t_min) * inv_dt;
        int b = (int)x;
        b = b < 0 ? 0 : (b > T_SAMPLES - 1 ? T_SAMPLES - 1 : b);
        unsigned of = (unsigned)(fminf(x - (float)b, 0.99999994f) * 32768.0f);
        atomicAdd(&h[subbase + b], CNT_ONE | of);
    }
    __syncthreads();

    // merge 16 sub-hists as split (count,ofs) -> transposed partial slot.
    // Split avoids cross-field carry when summing 16 packed words.
    if (threadIdx.x < T_SAMPLES) {
        unsigned cnt = 0u, ofs = 0u;
        #pragma unroll
        for (int s = 0; s < NSUB; ++s) {
            unsigned p = h[s * HPAD + threadIdx.x];
            cnt += p >> 23;
            ofs += p & OFS_MASK;
        }
        // store as two u32 planes (bin-major, block-minor)
        ((unsigned*)ws)[PART32 + (size_t)threadIdx.x * nb + blockIdx.x] = cnt;
        ((unsigned*)ws)[PART32 + (size_t)(T_SAMPLES + threadIdx.x) * nb + blockIdx.x] = ofs;
    }
}

// 100 blocks: block j reduces bin j's partials (contiguous); last block does finale.
__global__ void __launch_bounds__(THREADS) cvar_pass3(float* __restrict__ ws,
                                                      float* __restrict__ out,
                                                      int n, int nb) {
    __shared__ float smin[NWAVES], smax[NWAVES];
    __shared__ float s_tmin, s_tmax;
    __shared__ unsigned long long sc[NWAVES], so[NWAVES];
    __shared__ bool amLast;
    __shared__ double dc[T_SAMPLES], dofs[T_SAMPLES];
    __shared__ float sred[NWAVES];

    const unsigned* pc = (const unsigned*)ws + PART32 + (size_t)blockIdx.x * nb;
    const unsigned* po = (const unsigned*)ws + PART32 + (size_t)(T_SAMPLES + blockIdx.x) * nb;
    unsigned long long cnt = 0ull, ofs = 0ull;
    for (int b = threadIdx.x; b < nb; b += THREADS) {
        cnt += pc[b];
        ofs += po[b];
    }
    #pragma unroll
    for (int off = 32; off > 0; off >>= 1) {
        cnt += __shfl_down(cnt, off, 64);
        ofs += __shfl_down(ofs, off, 64);
    }
    int lane = threadIdx.x & 63, wid = threadIdx.x >> 6;
    if (lane == 0) { sc[wid] = cnt; so[wid] = ofs; }
    __syncthreads();
    if (threadIdx.x == 0) {
        unsigned long long C = sc[0], O = so[0];
        for (int w = 1; w < NWAVES; ++w) { C += sc[w]; O += so[w]; }
        ((double*)ws)[FINAL_C_D + blockIdx.x] = (double)C;
        ((double*)ws)[FINAL_O_D + blockIdx.x] = (double)O;
    }
    __syncthreads();

    // last-arriving block computes the finale (only 200 agent-scope loads)
    if (threadIdx.x == 0) {
        __threadfence();
        unsigned prev = atomicAdd((unsigned*)ws, 1u);
        amLast = (prev == (unsigned)(T_SAMPLES - 1));
    }
    __syncthreads();
    if (!amLast) return;
    __threadfence();

    reduce_minmax_partials(ws, &s_tmin, &s_tmax, smin, smax);
    const float t_min = s_tmin, t_max = s_tmax;
    const float range = t_max - t_min;
    const float dt = range / (float)(T_SAMPLES - 1);

    int j = threadIdx.x;
    if (j < T_SAMPLES) {
        dc[j] = __hip_atomic_load(&((double*)ws)[FINAL_C_D + j],
                                  __ATOMIC_RELAXED, __HIP_MEMORY_SCOPE_AGENT);
        dofs[j] = __hip_atomic_load(&((double*)ws)[FINAL_O_D + j],
                                    __ATOMIC_RELAXED, __HIP_MEMORY_SCOPE_AGENT);
    }
    __syncthreads();

    float cvar = INFINITY;
    if (j < T_SAMPLES) {
        double O = 0.0, W = 0.0;
        for (int k = j; k < T_SAMPLES; ++k) {
            O += dofs[k];
            W += (double)(k - j) * dc[k];
        }
        // S(t_j) = dt * [ O/2^15 + W ]
        double S = (double)dt * (O * (1.0 / 32768.0) + W);
        float tj = (j == T_SAMPLES - 1) ? t_max : t_min + (float)j * dt;
        cvar = tj + (float)(S * (20.0 / (double)n));
    }
    #pragma unroll
    for (int off = 32; off > 0; off >>= 1)
        cvar = fminf(cvar, __shfl_down(cvar, off, 64));
    if (lane == 0) sred[wid] = cvar;
    __syncthreads();
    if (threadIdx.x == 0) {
        float m = sred[0];
        for (int w = 1; w < NWAVES; ++w) m = fminf(m, sred[w]);
        out[0] = m;
    }
}

extern "C" void kernel_launch(void* const* d_in, const int* in_sizes, int n_in,
                              void* d_out, int out_size, void* d_ws, size_t ws_size,
                              hipStream_t stream) {
    const float* pnl = (const float*)d_in[0];
    int n = in_sizes[0];
    float* ws = (float*)d_ws;
    float* out = (float*)d_out;

    // nb between 512 (u32-pack overflow bound) and 1024, fitted to ws
    long avail_u32 = (long)(ws_size / 4) - PART32 - 1024;  // reserve finals tail
    int nb = (int)(avail_u32 / (2 * T_SAMPLES));
    nb = nb > HB_MAX ? HB_MAX : nb;
    nb = nb < HB_MIN ? HB_MIN : nb;

    cvar_pass1<<<K1_BLOCKS, THREADS, 0, stream>>>(pnl, n, ws);
    cvar_pass2<<<nb, THREADS, 0, stream>>>(pnl, n, ws, nb);
    cvar_pass3<<<T_SAMPLES, THREADS, 0, stream>>>(ws, out, n, nb);
}